// Round 13
// baseline (129.427 us; speedup 1.0000x reference)
//
#include <hip/hip_runtime.h>
#include <hip/hip_bf16.h>
#include <cstdint>

typedef __attribute__((ext_vector_type(8))) __bf16 bf16x8;
typedef __attribute__((ext_vector_type(4))) float f32x4;
typedef __attribute__((ext_vector_type(16))) float f32x16;

#define DM 1024
#define NH 16
#define DH 64
#define S_LEN 2048
#define BATCH 2

__device__ __forceinline__ ushort f2bf(float f) {
  union { float f; uint32_t u; } v; v.f = f;
  uint32_t u = v.u;
  uint32_t r = (u + 0x7fffu + ((u >> 16) & 1u)) >> 16;
  return (ushort)r;
}
__device__ __forceinline__ float bf2f(ushort h) {
  union { uint32_t u; float f; } v; v.u = ((uint32_t)h) << 16;
  return v.f;
}
__device__ __forceinline__ float bf2f_lo(uint32_t u) {
  union { uint32_t u; float f; } v; v.u = u << 16;
  return v.f;
}
__device__ __forceinline__ float bf2f_hi(uint32_t u) {
  union { uint32_t u; float f; } v; v.u = u & 0xffff0000u;
  return v.f;
}

__device__ __forceinline__ void gload16(const void* g, void* l) {
  __builtin_amdgcn_global_load_lds(
      (const __attribute__((address_space(1))) unsigned*)g,
      (__attribute__((address_space(3))) unsigned*)l, 16, 0, 0);
}

__device__ __forceinline__ float tsum16(const f32x16& v) {
  float a = (v[0] + v[1]) + (v[2] + v[3]);
  float b = (v[4] + v[5]) + (v[6] + v[7]);
  float c = (v[8] + v[9]) + (v[10] + v[11]);
  float d = (v[12] + v[13]) + (v[14] + v[15]);
  return (a + b) + (c + d);
}

// ---------------- prep: all f32->bf16 casts + rope table in one kernel ----------------
__global__ void prep(const float* __restrict__ x, const float* __restrict__ wqkv,
                     const float* __restrict__ wout,
                     ushort* __restrict__ xb, ushort* __restrict__ wqkvb,
                     ushort* __restrict__ woutb, float2* __restrict__ tab) {
  const int NX = 1048576, NW = 786432, NO = 262144, NT = 65536;
  for (int i = blockIdx.x * blockDim.x + threadIdx.x; i < NX + NW + NO + NT;
       i += gridDim.x * blockDim.x) {
    if (i < NX + NW + NO) {
      const float* src; ushort* dst; int j;
      if (i < NX)           { src = x;    dst = xb;    j = i; }
      else if (i < NX + NW) { src = wqkv; dst = wqkvb; j = i - NX; }
      else                  { src = wout; dst = woutb; j = i - NX - NW; }
      float4 v = ((const float4*)src)[j];
      ushort4 o;
      o.x = f2bf(v.x); o.y = f2bf(v.y); o.z = f2bf(v.z); o.w = f2bf(v.w);
      ((ushort4*)dst)[j] = o;
    } else {
      int j = i - NX - NW - NO;
      int fi = j & 31, s = j >> 5;
      float inv = expf(-(float)fi * (9.210340371976184f / 32.0f));
      float ang = (float)s * inv;
      float sn, cs;
      sincosf(ang, &sn, &cs);
      tab[j] = make_float2(cs, sn);
    }
  }
}

// ---------------- fused QKV GEMM + LDS-staged rope/transpose epilogue (unchanged) ----------------
__global__ __launch_bounds__(256) void gemm_qkv(
    const ushort* __restrict__ A, const ushort* __restrict__ B,
    const float2* __restrict__ tab,
    ushort* __restrict__ Qh, ushort* __restrict__ Kh, ushort* __restrict__ Vt)
{
  union SM {
    struct { ushort As[128][64]; ushort Bs[128][64]; } s;
    ushort vt[128][136];
  };
  __shared__ __align__(16) SM sm;

  const int K = 1024;
  const int t = threadIdx.x;
  const int w = t >> 6, lane = t & 63;
  const int wm = w >> 1, wn = w & 1;
  const int lr = lane & 15, lk = lane >> 4;
  const int m0 = blockIdx.y * 128, n0 = blockIdx.x * 128;

  const int srow8 = lane >> 3;
  const int scol  = ((lane & 7) ^ srow8) * 8;

  f32x4 acc[4][4];
#pragma unroll
  for (int m = 0; m < 4; m++)
#pragma unroll
    for (int n = 0; n < 4; n++) acc[m][n] = (f32x4)(0.0f);

  for (int k0 = 0; k0 < K; k0 += 64) {
#pragma unroll
    for (int j = 0; j < 4; ++j) {
      const int c = w * 4 + j;
      const int row = c * 8 + srow8;
      gload16(&A[(size_t)(m0 + row) * K + k0 + scol], &sm.s.As[c * 8][0]);
      gload16(&B[(size_t)(n0 + row) * K + k0 + scol], &sm.s.Bs[c * 8][0]);
    }
    __syncthreads();

    bf16x8 af[4][2], bfr[4][2];
#pragma unroll
    for (int m = 0; m < 4; m++)
#pragma unroll
      for (int kk = 0; kk < 2; kk++) {
        const int ch = (((kk << 2) + lk) ^ (lr & 7)) * 8;
        af[m][kk] = *(const bf16x8*)&sm.s.As[wm * 64 + m * 16 + lr][ch];
      }
#pragma unroll
    for (int n = 0; n < 4; n++)
#pragma unroll
      for (int kk = 0; kk < 2; kk++) {
        const int ch = (((kk << 2) + lk) ^ (lr & 7)) * 8;
        bfr[n][kk] = *(const bf16x8*)&sm.s.Bs[wn * 64 + n * 16 + lr][ch];
      }

    __builtin_amdgcn_s_setprio(1);
#pragma unroll
    for (int kk = 0; kk < 2; kk++)
#pragma unroll
      for (int m = 0; m < 4; m++)
#pragma unroll
        for (int n = 0; n < 4; n++)
          acc[m][n] = __builtin_amdgcn_mfma_f32_16x16x32_bf16(af[m][kk], bfr[n][kk], acc[m][n], 0, 0, 0);
    __builtin_amdgcn_s_setprio(0);

    __syncthreads();
  }

  const int reg  = n0 >> 10;
  const int cb   = n0 & 1023;
  const int b    = m0 >> 11;
  const int s0   = m0 & 2047;
  const int h0   = cb >> 6;

#pragma unroll
  for (int m = 0; m < 4; m++)
#pragma unroll
    for (int n = 0; n < 4; n++)
#pragma unroll
      for (int r = 0; r < 4; r++)
        sm.vt[wm * 64 + m * 16 + lk * 4 + r][wn * 64 + n * 16 + lr] = f2bf(acc[m][n][r]);
  __syncthreads();

  if (reg < 2) {
    ushort* dst = reg ? Kh : Qh;
    const float qs = reg ? 1.0f : 0.125f * 1.4426950408889634f;
#pragma unroll
    for (int p = 0; p < 8; ++p) {
      const int tid = t + p * 256;
      const int srow = tid >> 4;
      const int c8 = tid & 15;
      const int h = h0 + (c8 >> 3), d8 = (c8 & 7) * 8;
      const int s = s0 + srow;
      const ushort* lp = &sm.vt[srow][c8 * 8];
      float4 t0 = *(const float4*)&tab[s * 32 + (c8 & 7) * 4];
      float4 t1 = *(const float4*)&tab[s * 32 + (c8 & 7) * 4 + 2];
      uint32_t ow[4];
#pragma unroll
      for (int j = 0; j < 4; ++j) {
        float2 cs2 = (j < 2) ? ((const float2*)&t0)[j] : ((const float2*)&t1)[j - 2];
        float xr = bf2f(lp[2 * j]), xi = bf2f(lp[2 * j + 1]);
        float orr = (xr * cs2.x - xi * cs2.y) * qs;
        float oii = (xr * cs2.y + xi * cs2.x) * qs;
        ow[j] = (uint32_t)f2bf(orr) | ((uint32_t)f2bf(oii) << 16);
      }
      *(uint4*)&dst[((size_t)((b * NH + h) * S_LEN + s)) * 64 + d8] = *(const uint4*)ow;
    }
  } else {
#pragma unroll
    for (int p = 0; p < 8; ++p) {
      const int tid = t + p * 256;
      const int cl = tid >> 4;
      const int s8 = (tid & 15) * 8;
      const int h = h0 + (cl >> 6), d = cl & 63;
      ushort tmp[8];
#pragma unroll
      for (int j = 0; j < 8; j++) tmp[j] = sm.vt[s8 + j][cl];
      *(uint4*)&Vt[((size_t)((b * NH + h) * 64 + d)) * S_LEN + s0 + s8] = *(const uint4*)tmp;
    }
  }
}

// ---------------- out-proj GEMM with async dual-buffer split-KV merge ----------------
// C[4096,1024] = merge(op halves) @ woutb^T. Both op halves staged via
// global_load_lds (async) into As1/As2; weighted merge at fragment-build time
// with per-row scales s_i = l_i/(l1+l2) loaded per K-step (head = k0>>6).
// Indexing identical to R11's verified-correct version; staging now async.
__global__ __launch_bounds__(256) void gemm_out(
    const ushort* __restrict__ op, const float* __restrict__ lso,
    const ushort* __restrict__ B, float* __restrict__ Cv)
{
  const int N = 1024, K = 1024;
  __shared__ ushort As1[128][64];
  __shared__ ushort As2[128][64];
  __shared__ ushort Bs[128][64];
  const int t = threadIdx.x;
  const int w = t >> 6, lane = t & 63;
  const int wm = w >> 1, wn = w & 1;
  const int lr = lane & 15, lk = lane >> 4;
  const int m0 = blockIdx.y * 128, n0 = blockIdx.x * 128;

  const int srow8 = lane >> 3;
  const int scol  = ((lane & 7) ^ srow8) * 8;

  const int b  = m0 >> 11;     // uniform per block (128 | 2048)
  const int s0 = m0 & 2047;

  f32x4 acc[4][4];
#pragma unroll
  for (int m = 0; m < 4; m++)
#pragma unroll
    for (int n = 0; n < 4; n++) acc[m][n] = (f32x4)(0.0f);

  for (int k0 = 0; k0 < K; k0 += 64) {
    const int h = k0 >> 6;                               // uniform head this step
    const size_t hb = (size_t)(b * NH + h) * S_LEN;      // row base in op/lso
#pragma unroll
    for (int j = 0; j < 4; ++j) {
      const int c = w * 4 + j;
      const int row = c * 8 + srow8;
      gload16(&B[(size_t)(n0 + row) * K + k0 + scol], &Bs[c * 8][0]);
      const size_t oi = (hb + s0 + row) * 64 + scol;
      gload16(&op[oi],           &As1[c * 8][0]);
      gload16(&op[4194304 + oi], &As2[c * 8][0]);
    }
    // per-lane merge scales for this head (4 A-rows per lane)
    float s1[4], s2[4];
#pragma unroll
    for (int m = 0; m < 4; ++m) {
      const size_t li = hb + s0 + wm * 64 + m * 16 + lr;
      const float l1 = lso[li], l2 = lso[65536 + li];
      const float si = 1.0f / (l1 + l2);
      s1[m] = l1 * si; s2[m] = l2 * si;
    }
    __syncthreads();

    bf16x8 af[4][2], bfr[4][2];
#pragma unroll
    for (int m = 0; m < 4; m++)
#pragma unroll
      for (int kk = 0; kk < 2; kk++) {
        const int ch = (((kk << 2) + lk) ^ (lr & 7)) * 8;
        const uint32_t* a1 = (const uint32_t*)&As1[wm * 64 + m * 16 + lr][ch];
        const uint32_t* a2 = (const uint32_t*)&As2[wm * 64 + m * 16 + lr][ch];
        union { uint32_t u[4]; bf16x8 v; } o;
#pragma unroll
        for (int q = 0; q < 4; ++q) {
          float lo = s1[m] * bf2f_lo(a1[q]) + s2[m] * bf2f_lo(a2[q]);
          float hi = s1[m] * bf2f_hi(a1[q]) + s2[m] * bf2f_hi(a2[q]);
          asm("v_cvt_pk_bf16_f32 %0, %1, %2" : "=v"(o.u[q]) : "v"(lo), "v"(hi));
        }
        af[m][kk] = o.v;
      }
#pragma unroll
    for (int n = 0; n < 4; n++)
#pragma unroll
      for (int kk = 0; kk < 2; kk++) {
        const int ch = (((kk << 2) + lk) ^ (lr & 7)) * 8;
        bfr[n][kk] = *(const bf16x8*)&Bs[wn * 64 + n * 16 + lr][ch];
      }

    __builtin_amdgcn_s_setprio(1);
#pragma unroll
    for (int kk = 0; kk < 2; kk++)
#pragma unroll
      for (int m = 0; m < 4; m++)
#pragma unroll
        for (int n = 0; n < 4; n++)
          acc[m][n] = __builtin_amdgcn_mfma_f32_16x16x32_bf16(af[m][kk], bfr[n][kk], acc[m][n], 0, 0, 0);
    __builtin_amdgcn_s_setprio(0);

    __syncthreads();
  }

#pragma unroll
  for (int m = 0; m < 4; m++) {
    int row = m0 + wm * 64 + m * 16 + lk * 4;
#pragma unroll
    for (int n = 0; n < 4; n++) {
      int col = n0 + wn * 64 + n * 16 + lr;
#pragma unroll
      for (int r = 0; r < 4; r++)
        Cv[(size_t)(row + r) * N + col] = acc[m][n][r];
    }
  }
}

// ---------------- causal flash attention v7: split-KV, fixed-m softmax (unchanged) ----------------
union SMemU {
  struct { ushort K[2][64][64]; ushort V[2][64][64]; } kv;  // 32 KB
  ushort Ot[128][68];
};

__global__ __launch_bounds__(256) void flash_attn7(
    const ushort* __restrict__ Qh, const ushort* __restrict__ Kh, const ushort* __restrict__ Vt,
    ushort* __restrict__ op, float* __restrict__ lso)
{
  __shared__ __align__(16) SMemU sm;

  const int bh = blockIdx.x;
  const int qt = 15 - blockIdx.y;
  const int half = blockIdx.z;
  const int t = threadIdx.x;
  const int w = t >> 6, lane = t & 63;
  const int q5 = lane & 31, hi = lane >> 5;

  const int qbase_w = qt * 128 + w * 32;
  const int qg = qbase_w + q5;

  bf16x8 qreg[4];
  {
    const size_t qb = ((size_t)bh * S_LEN + qg) * 64;
#pragma unroll
    for (int c = 0; c < 4; ++c)
      qreg[c] = *(const bf16x8*)&Qh[qb + c * 16 + hi * 8];
  }

  f32x16 oacc[2];
  oacc[0] = (f32x16)(0.0f); oacc[1] = (f32x16)(0.0f);
  float lsum = 0.0f;

  const ushort* Kg = &Kh[((size_t)bh * S_LEN) * 64];
  const ushort* Vg = &Vt[((size_t)bh * 64) * S_LEN];

  auto STAGE = [&](int bf, int jt) {
#pragma unroll
    for (int p = 0; p < 2; ++p) {
      const int row = w * 16 + p * 8 + (lane >> 3);
      const int c16 = (lane & 7) ^ (row & 7);
      gload16(&Kg[((size_t)(jt * 64 + row)) * 64 + c16 * 8], &sm.kv.K[bf][w * 16 + p * 8][0]);
      gload16(&Vg[((size_t)row) * S_LEN + jt * 64 + c16 * 8], &sm.kv.V[bf][w * 16 + p * 8][0]);
    }
  };

  const int j0 = half ? (qt + 1) : 0;
  const int j1 = half ? (2 * qt + 2) : (qt + 1);

  STAGE(0, j0);
  __syncthreads();

  int cur = 0;
  for (int jt = j0; jt < j1; ++jt) {
    if (jt + 1 < j1) STAGE(cur ^ 1, jt + 1);

    const bool active = (jt * 64 <= qbase_w + 31);
    if (active) {
      f32x16 sc[2];
      sc[0] = (f32x16)(0.0f); sc[1] = (f32x16)(0.0f);
      __builtin_amdgcn_s_setprio(1);
#pragma unroll
      for (int kg = 0; kg < 2; ++kg) {
        const int kr = kg * 32 + q5;
#pragma unroll
        for (int c = 0; c < 4; ++c) {
          bf16x8 kf = *(const bf16x8*)&sm.kv.K[cur][kr][((c * 2 + hi) ^ (kr & 7)) * 8];
          sc[kg] = __builtin_amdgcn_mfma_f32_32x32x16_bf16(kf, qreg[c], sc[kg], 0, 0, 0);
        }
      }
      __builtin_amdgcn_s_setprio(0);

      if (jt * 64 + 63 > qbase_w) {
        const int kb = jt * 64;
#pragma unroll
        for (int r = 0; r < 16; ++r) {
          const int kl = kb + (r & 3) + 8 * (r >> 2) + 4 * hi;
          if (kl > qg)      sc[0][r] = -1e30f;
          if (kl + 32 > qg) sc[1][r] = -1e30f;
        }
      }

#pragma unroll
      for (int kg = 0; kg < 2; ++kg)
#pragma unroll
        for (int r = 0; r < 16; ++r)
          sc[kg][r] = __builtin_amdgcn_exp2f(sc[kg][r]);
      float rsum = tsum16(sc[0]) + tsum16(sc[1]);
      rsum += __shfl_xor(rsum, 32, 64);
      lsum += rsum;

      bf16x8 pf[4];
#pragma unroll
      for (int kc = 0; kc < 4; ++kc) {
        const int kg = kc >> 1, rA = (kc & 1) * 8, rB = rA + 4;
        uint32_t A0, A1, B0, B1;
        asm("v_cvt_pk_bf16_f32 %0, %1, %2" : "=v"(A0) : "v"(sc[kg][rA + 0]), "v"(sc[kg][rA + 1]));
        asm("v_cvt_pk_bf16_f32 %0, %1, %2" : "=v"(A1) : "v"(sc[kg][rA + 2]), "v"(sc[kg][rA + 3]));
        asm("v_cvt_pk_bf16_f32 %0, %1, %2" : "=v"(B0) : "v"(sc[kg][rB + 0]), "v"(sc[kg][rB + 1]));
        asm("v_cvt_pk_bf16_f32 %0, %1, %2" : "=v"(B1) : "v"(sc[kg][rB + 2]), "v"(sc[kg][rB + 3]));
        asm("v_permlane32_swap_b32 %0, %1" : "+v"(A0), "+v"(B0));
        asm("v_permlane32_swap_b32 %0, %1" : "+v"(A1), "+v"(B1));
        union { uint32_t u[4]; bf16x8 v; } cv;
        cv.u[0] = A0; cv.u[1] = A1; cv.u[2] = B0; cv.u[3] = B1;
        pf[kc] = cv.v;
      }

      __builtin_amdgcn_s_setprio(1);
#pragma unroll
      for (int dg = 0; dg < 2; ++dg) {
        const int vr = dg * 32 + q5;
#pragma unroll
        for (int kc = 0; kc < 4; ++kc) {
          bf16x8 vf = *(const bf16x8*)&sm.kv.V[cur][vr][((kc * 2 + hi) ^ (vr & 7)) * 8];
          oacc[dg] = __builtin_amdgcn_mfma_f32_32x32x16_bf16(vf, pf[kc], oacc[dg], 0, 0, 0);
        }
      }
      __builtin_amdgcn_s_setprio(0);
    }

    __syncthreads();
    cur ^= 1;
  }

  if (hi == 0)
    lso[(size_t)(half * 32 + bh) * S_LEN + qg] = lsum;

  const float inv = (lsum > 0.0f) ? (1.0f / lsum) : 0.0f;
#pragma unroll
  for (int dg = 0; dg < 2; ++dg)
#pragma unroll
    for (int g = 0; g < 4; ++g) {
      ushort4 ok;
      ok.x = f2bf(oacc[dg][4 * g + 0] * inv); ok.y = f2bf(oacc[dg][4 * g + 1] * inv);
      ok.z = f2bf(oacc[dg][4 * g + 2] * inv); ok.w = f2bf(oacc[dg][4 * g + 3] * inv);
      *(ushort4*)&sm.Ot[w * 32 + q5][dg * 32 + g * 8 + 4 * hi] = ok;
    }
  __syncthreads();
  {
    const int row = t >> 1, c32 = (t & 1) * 32;
    const size_t gb = ((size_t)(half * 32 + bh) * S_LEN + qt * 128 + row) * 64 + c32;
#pragma unroll
    for (int j = 0; j < 4; ++j)
      *(uint4*)&op[gb + j * 8] = *(const uint4*)&sm.Ot[row][c32 + j * 8];
  }
}

extern "C" void kernel_launch(void* const* d_in, const int* in_sizes, int n_in,
                              void* d_out, int out_size, void* d_ws, size_t ws_size,
                              hipStream_t stream) {
  const float* x     = (const float*)d_in[0];
  const float* w_qkv = (const float*)d_in[2];
  const float* w_out = (const float*)d_in[3];
  float* out = (float*)d_out;

  char* ws = (char*)d_ws;
  ushort* xb    = (ushort*)(ws);
  ushort* wqkvb = (ushort*)(ws + 8388608);
  ushort* woutb = (ushort*)(ws + 14680064);
  ushort* Qh    = (ushort*)(ws + 41943040);
  ushort* Kh    = (ushort*)(ws + 50331648);
  ushort* Vt    = (ushort*)(ws + 58720256);
  float2* tab   = (float2*)(ws + 75497472);
  ushort* op    = (ushort*)(ws + 16777216);   // 16 MB: (2,32,2048,64) bf16
  float*  lso   = (float*)(ws + 33554432);    // 512 KB: (2,32,2048) float

  prep<<<2048, 256, 0, stream>>>(x, w_qkv, w_out, xb, wqkvb, woutb, tab);

  gemm_qkv<<<dim3(24, 32), 256, 0, stream>>>(xb, wqkvb, tab, Qh, Kh, Vt);

  flash_attn7<<<dim3(32, 16, 2), 256, 0, stream>>>(Qh, Kh, Vt, op, lso);

  gemm_out<<<dim3(8, 32), 256, 0, stream>>>(op, lso, woutb, out);
}

// Round 14
// 111.784 us; speedup vs baseline: 1.1578x; 1.1578x over previous
//
#include <hip/hip_runtime.h>
#include <hip/hip_bf16.h>
#include <cstdint>

typedef __attribute__((ext_vector_type(8))) __bf16 bf16x8;
typedef __attribute__((ext_vector_type(4))) float f32x4;
typedef __attribute__((ext_vector_type(16))) float f32x16;

#define DM 1024
#define NH 16
#define DH 64
#define S_LEN 2048
#define BATCH 2

__device__ __forceinline__ ushort f2bf(float f) {
  union { float f; uint32_t u; } v; v.f = f;
  uint32_t u = v.u;
  uint32_t r = (u + 0x7fffu + ((u >> 16) & 1u)) >> 16;
  return (ushort)r;
}
__device__ __forceinline__ float bf2f(ushort h) {
  union { uint32_t u; float f; } v; v.u = ((uint32_t)h) << 16;
  return v.f;
}
__device__ __forceinline__ float bf2f_lo(uint32_t u) {
  union { uint32_t u; float f; } v; v.u = u << 16;
  return v.f;
}
__device__ __forceinline__ float bf2f_hi(uint32_t u) {
  union { uint32_t u; float f; } v; v.u = u & 0xffff0000u;
  return v.f;
}

__device__ __forceinline__ void gload16(const void* g, void* l) {
  __builtin_amdgcn_global_load_lds(
      (const __attribute__((address_space(1))) unsigned*)g,
      (__attribute__((address_space(3))) unsigned*)l, 16, 0, 0);
}

__device__ __forceinline__ float tsum16(const f32x16& v) {
  float a = (v[0] + v[1]) + (v[2] + v[3]);
  float b = (v[4] + v[5]) + (v[6] + v[7]);
  float c = (v[8] + v[9]) + (v[10] + v[11]);
  float d = (v[12] + v[13]) + (v[14] + v[15]);
  return (a + b) + (c + d);
}

// ---------------- prep: all f32->bf16 casts + rope table in one kernel ----------------
__global__ void prep(const float* __restrict__ x, const float* __restrict__ wqkv,
                     const float* __restrict__ wout,
                     ushort* __restrict__ xb, ushort* __restrict__ wqkvb,
                     ushort* __restrict__ woutb, float2* __restrict__ tab) {
  const int NX = 1048576, NW = 786432, NO = 262144, NT = 65536;
  for (int i = blockIdx.x * blockDim.x + threadIdx.x; i < NX + NW + NO + NT;
       i += gridDim.x * blockDim.x) {
    if (i < NX + NW + NO) {
      const float* src; ushort* dst; int j;
      if (i < NX)           { src = x;    dst = xb;    j = i; }
      else if (i < NX + NW) { src = wqkv; dst = wqkvb; j = i - NX; }
      else                  { src = wout; dst = woutb; j = i - NX - NW; }
      float4 v = ((const float4*)src)[j];
      ushort4 o;
      o.x = f2bf(v.x); o.y = f2bf(v.y); o.z = f2bf(v.z); o.w = f2bf(v.w);
      ((ushort4*)dst)[j] = o;
    } else {
      int j = i - NX - NW - NO;
      int fi = j & 31, s = j >> 5;
      float inv = expf(-(float)fi * (9.210340371976184f / 32.0f));
      float ang = (float)s * inv;
      float sn, cs;
      sincosf(ang, &sn, &cs);
      tab[j] = make_float2(cs, sn);
    }
  }
}

// ---------------- fused QKV GEMM + LDS-staged rope/transpose epilogue ----------------
__global__ __launch_bounds__(256) void gemm_qkv(
    const ushort* __restrict__ A, const ushort* __restrict__ B,
    const float2* __restrict__ tab,
    ushort* __restrict__ Qh, ushort* __restrict__ Kh, ushort* __restrict__ Vt)
{
  union SM {
    struct { ushort As[128][64]; ushort Bs[128][64]; } s;
    ushort vt[128][136];
  };
  __shared__ __align__(16) SM sm;

  const int K = 1024;
  const int t = threadIdx.x;
  const int w = t >> 6, lane = t & 63;
  const int wm = w >> 1, wn = w & 1;
  const int lr = lane & 15, lk = lane >> 4;
  const int m0 = blockIdx.y * 128, n0 = blockIdx.x * 128;

  const int srow8 = lane >> 3;
  const int scol  = ((lane & 7) ^ srow8) * 8;

  f32x4 acc[4][4];
#pragma unroll
  for (int m = 0; m < 4; m++)
#pragma unroll
    for (int n = 0; n < 4; n++) acc[m][n] = (f32x4)(0.0f);

  for (int k0 = 0; k0 < K; k0 += 64) {
#pragma unroll
    for (int j = 0; j < 4; ++j) {
      const int c = w * 4 + j;
      const int row = c * 8 + srow8;
      gload16(&A[(size_t)(m0 + row) * K + k0 + scol], &sm.s.As[c * 8][0]);
      gload16(&B[(size_t)(n0 + row) * K + k0 + scol], &sm.s.Bs[c * 8][0]);
    }
    __syncthreads();

    bf16x8 af[4][2], bfr[4][2];
#pragma unroll
    for (int m = 0; m < 4; m++)
#pragma unroll
      for (int kk = 0; kk < 2; kk++) {
        const int ch = (((kk << 2) + lk) ^ (lr & 7)) * 8;
        af[m][kk] = *(const bf16x8*)&sm.s.As[wm * 64 + m * 16 + lr][ch];
      }
#pragma unroll
    for (int n = 0; n < 4; n++)
#pragma unroll
      for (int kk = 0; kk < 2; kk++) {
        const int ch = (((kk << 2) + lk) ^ (lr & 7)) * 8;
        bfr[n][kk] = *(const bf16x8*)&sm.s.Bs[wn * 64 + n * 16 + lr][ch];
      }

    __builtin_amdgcn_s_setprio(1);
#pragma unroll
    for (int kk = 0; kk < 2; kk++)
#pragma unroll
      for (int m = 0; m < 4; m++)
#pragma unroll
        for (int n = 0; n < 4; n++)
          acc[m][n] = __builtin_amdgcn_mfma_f32_16x16x32_bf16(af[m][kk], bfr[n][kk], acc[m][n], 0, 0, 0);
    __builtin_amdgcn_s_setprio(0);

    __syncthreads();
  }

  const int reg  = n0 >> 10;
  const int cb   = n0 & 1023;
  const int b    = m0 >> 11;
  const int s0   = m0 & 2047;
  const int h0   = cb >> 6;

#pragma unroll
  for (int m = 0; m < 4; m++)
#pragma unroll
    for (int n = 0; n < 4; n++)
#pragma unroll
      for (int r = 0; r < 4; r++)
        sm.vt[wm * 64 + m * 16 + lk * 4 + r][wn * 64 + n * 16 + lr] = f2bf(acc[m][n][r]);
  __syncthreads();

  if (reg < 2) {
    ushort* dst = reg ? Kh : Qh;
    const float qs = reg ? 1.0f : 0.125f * 1.4426950408889634f;
#pragma unroll
    for (int p = 0; p < 8; ++p) {
      const int tid = t + p * 256;
      const int srow = tid >> 4;
      const int c8 = tid & 15;
      const int h = h0 + (c8 >> 3), d8 = (c8 & 7) * 8;
      const int s = s0 + srow;
      const ushort* lp = &sm.vt[srow][c8 * 8];
      float4 t0 = *(const float4*)&tab[s * 32 + (c8 & 7) * 4];
      float4 t1 = *(const float4*)&tab[s * 32 + (c8 & 7) * 4 + 2];
      uint32_t ow[4];
#pragma unroll
      for (int j = 0; j < 4; ++j) {
        float2 cs2 = (j < 2) ? ((const float2*)&t0)[j] : ((const float2*)&t1)[j - 2];
        float xr = bf2f(lp[2 * j]), xi = bf2f(lp[2 * j + 1]);
        float orr = (xr * cs2.x - xi * cs2.y) * qs;
        float oii = (xr * cs2.y + xi * cs2.x) * qs;
        ow[j] = (uint32_t)f2bf(orr) | ((uint32_t)f2bf(oii) << 16);
      }
      *(uint4*)&dst[((size_t)((b * NH + h) * S_LEN + s)) * 64 + d8] = *(const uint4*)ow;
    }
  } else {
#pragma unroll
    for (int p = 0; p < 8; ++p) {
      const int tid = t + p * 256;
      const int cl = tid >> 4;
      const int s8 = (tid & 15) * 8;
      const int h = h0 + (cl >> 6), d = cl & 63;
      ushort tmp[8];
#pragma unroll
      for (int j = 0; j < 8; j++) tmp[j] = sm.vt[s8 + j][cl];
      *(uint4*)&Vt[((size_t)((b * NH + h) * 64 + d)) * S_LEN + s0 + s8] = *(const uint4*)tmp;
    }
  }
}

// ---------------- GEMM v4 (async-staged, for out-proj) ----------------
template<int WRITE_BF16>
__global__ __launch_bounds__(256) void gemm_bt4(
    const ushort* __restrict__ A, const ushort* __restrict__ B,
    void* __restrict__ Cv, int M, int N, int K)
{
  __shared__ ushort As[128][64];
  __shared__ ushort Bs[128][64];
  const int t = threadIdx.x;
  const int w = t >> 6, lane = t & 63;
  const int wm = w >> 1, wn = w & 1;
  const int lr = lane & 15, lk = lane >> 4;
  const int m0 = blockIdx.y * 128, n0 = blockIdx.x * 128;

  const int srow8 = lane >> 3;
  const int scol  = ((lane & 7) ^ srow8) * 8;

  f32x4 acc[4][4];
#pragma unroll
  for (int m = 0; m < 4; m++)
#pragma unroll
    for (int n = 0; n < 4; n++) acc[m][n] = (f32x4)(0.0f);

  for (int k0 = 0; k0 < K; k0 += 64) {
#pragma unroll
    for (int j = 0; j < 4; ++j) {
      const int c = w * 4 + j;
      const int row = c * 8 + srow8;
      gload16(&A[(size_t)(m0 + row) * K + k0 + scol], &As[c * 8][0]);
      gload16(&B[(size_t)(n0 + row) * K + k0 + scol], &Bs[c * 8][0]);
    }
    __syncthreads();

    bf16x8 af[4][2], bfr[4][2];
#pragma unroll
    for (int m = 0; m < 4; m++)
#pragma unroll
      for (int kk = 0; kk < 2; kk++) {
        const int ch = (((kk << 2) + lk) ^ (lr & 7)) * 8;
        af[m][kk] = *(const bf16x8*)&As[wm * 64 + m * 16 + lr][ch];
      }
#pragma unroll
    for (int n = 0; n < 4; n++)
#pragma unroll
      for (int kk = 0; kk < 2; kk++) {
        const int ch = (((kk << 2) + lk) ^ (lr & 7)) * 8;
        bfr[n][kk] = *(const bf16x8*)&Bs[wn * 64 + n * 16 + lr][ch];
      }

    __builtin_amdgcn_s_setprio(1);
#pragma unroll
    for (int kk = 0; kk < 2; kk++)
#pragma unroll
      for (int m = 0; m < 4; m++)
#pragma unroll
        for (int n = 0; n < 4; n++)
          acc[m][n] = __builtin_amdgcn_mfma_f32_16x16x32_bf16(af[m][kk], bfr[n][kk], acc[m][n], 0, 0, 0);
    __builtin_amdgcn_s_setprio(0);

    __syncthreads();
  }

#pragma unroll
  for (int m = 0; m < 4; m++) {
    int row = m0 + wm * 64 + m * 16 + lk * 4;
#pragma unroll
    for (int n = 0; n < 4; n++) {
      int col = n0 + wn * 64 + n * 16 + lr;
#pragma unroll
      for (int r = 0; r < 4; r++) {
        float val = acc[m][n][r];
        if (WRITE_BF16) ((ushort*)Cv)[(size_t)(row + r) * N + col] = f2bf(val);
        else            ((float*)Cv)[(size_t)(row + r) * N + col] = val;
      }
    }
  }
}

// ---------------- causal flash attention v7: split-KV, fixed-m softmax ----------------
union SMemU {
  struct { ushort K[2][64][64]; ushort V[2][64][64]; } kv;  // 32 KB
  ushort Ot[128][68];
};

__global__ __launch_bounds__(256) void flash_attn7(
    const ushort* __restrict__ Qh, const ushort* __restrict__ Kh, const ushort* __restrict__ Vt,
    ushort* __restrict__ op, float* __restrict__ lso)
{
  __shared__ __align__(16) SMemU sm;

  const int bh = blockIdx.x;
  const int qt = 15 - blockIdx.y;
  const int half = blockIdx.z;
  const int t = threadIdx.x;
  const int w = t >> 6, lane = t & 63;
  const int q5 = lane & 31, hi = lane >> 5;

  const int qbase_w = qt * 128 + w * 32;
  const int qg = qbase_w + q5;

  bf16x8 qreg[4];
  {
    const size_t qb = ((size_t)bh * S_LEN + qg) * 64;
#pragma unroll
    for (int c = 0; c < 4; ++c)
      qreg[c] = *(const bf16x8*)&Qh[qb + c * 16 + hi * 8];
  }

  f32x16 oacc[2];
  oacc[0] = (f32x16)(0.0f); oacc[1] = (f32x16)(0.0f);
  float lsum = 0.0f;

  const ushort* Kg = &Kh[((size_t)bh * S_LEN) * 64];
  const ushort* Vg = &Vt[((size_t)bh * 64) * S_LEN];

  auto STAGE = [&](int bf, int jt) {
#pragma unroll
    for (int p = 0; p < 2; ++p) {
      const int row = w * 16 + p * 8 + (lane >> 3);
      const int c16 = (lane & 7) ^ (row & 7);
      gload16(&Kg[((size_t)(jt * 64 + row)) * 64 + c16 * 8], &sm.kv.K[bf][w * 16 + p * 8][0]);
      gload16(&Vg[((size_t)row) * S_LEN + jt * 64 + c16 * 8], &sm.kv.V[bf][w * 16 + p * 8][0]);
    }
  };

  const int j0 = half ? (qt + 1) : 0;
  const int j1 = half ? (2 * qt + 2) : (qt + 1);

  STAGE(0, j0);
  __syncthreads();

  int cur = 0;
  for (int jt = j0; jt < j1; ++jt) {
    if (jt + 1 < j1) STAGE(cur ^ 1, jt + 1);

    const bool active = (jt * 64 <= qbase_w + 31);
    if (active) {
      f32x16 sc[2];
      sc[0] = (f32x16)(0.0f); sc[1] = (f32x16)(0.0f);
      __builtin_amdgcn_s_setprio(1);
#pragma unroll
      for (int kg = 0; kg < 2; ++kg) {
        const int kr = kg * 32 + q5;
#pragma unroll
        for (int c = 0; c < 4; ++c) {
          bf16x8 kf = *(const bf16x8*)&sm.kv.K[cur][kr][((c * 2 + hi) ^ (kr & 7)) * 8];
          sc[kg] = __builtin_amdgcn_mfma_f32_32x32x16_bf16(kf, qreg[c], sc[kg], 0, 0, 0);
        }
      }
      __builtin_amdgcn_s_setprio(0);

      if (jt * 64 + 63 > qbase_w) {
        const int kb = jt * 64;
#pragma unroll
        for (int r = 0; r < 16; ++r) {
          const int kl = kb + (r & 3) + 8 * (r >> 2) + 4 * hi;
          if (kl > qg)      sc[0][r] = -1e30f;
          if (kl + 32 > qg) sc[1][r] = -1e30f;
        }
      }

#pragma unroll
      for (int kg = 0; kg < 2; ++kg)
#pragma unroll
        for (int r = 0; r < 16; ++r)
          sc[kg][r] = __builtin_amdgcn_exp2f(sc[kg][r]);
      float rsum = tsum16(sc[0]) + tsum16(sc[1]);
      rsum += __shfl_xor(rsum, 32, 64);
      lsum += rsum;

      bf16x8 pf[4];
#pragma unroll
      for (int kc = 0; kc < 4; ++kc) {
        const int kg = kc >> 1, rA = (kc & 1) * 8, rB = rA + 4;
        uint32_t A0, A1, B0, B1;
        asm("v_cvt_pk_bf16_f32 %0, %1, %2" : "=v"(A0) : "v"(sc[kg][rA + 0]), "v"(sc[kg][rA + 1]));
        asm("v_cvt_pk_bf16_f32 %0, %1, %2" : "=v"(A1) : "v"(sc[kg][rA + 2]), "v"(sc[kg][rA + 3]));
        asm("v_cvt_pk_bf16_f32 %0, %1, %2" : "=v"(B0) : "v"(sc[kg][rB + 0]), "v"(sc[kg][rB + 1]));
        asm("v_cvt_pk_bf16_f32 %0, %1, %2" : "=v"(B1) : "v"(sc[kg][rB + 2]), "v"(sc[kg][rB + 3]));
        asm("v_permlane32_swap_b32 %0, %1" : "+v"(A0), "+v"(B0));
        asm("v_permlane32_swap_b32 %0, %1" : "+v"(A1), "+v"(B1));
        union { uint32_t u[4]; bf16x8 v; } cv;
        cv.u[0] = A0; cv.u[1] = A1; cv.u[2] = B0; cv.u[3] = B1;
        pf[kc] = cv.v;
      }

      __builtin_amdgcn_s_setprio(1);
#pragma unroll
      for (int dg = 0; dg < 2; ++dg) {
        const int vr = dg * 32 + q5;
#pragma unroll
        for (int kc = 0; kc < 4; ++kc) {
          bf16x8 vf = *(const bf16x8*)&sm.kv.V[cur][vr][((kc * 2 + hi) ^ (vr & 7)) * 8];
          oacc[dg] = __builtin_amdgcn_mfma_f32_32x32x16_bf16(vf, pf[kc], oacc[dg], 0, 0, 0);
        }
      }
      __builtin_amdgcn_s_setprio(0);
    }

    __syncthreads();
    cur ^= 1;
  }

  if (hi == 0)
    lso[(size_t)(half * 32 + bh) * S_LEN + qg] = lsum;

  const float inv = (lsum > 0.0f) ? (1.0f / lsum) : 0.0f;
#pragma unroll
  for (int dg = 0; dg < 2; ++dg)
#pragma unroll
    for (int g = 0; g < 4; ++g) {
      ushort4 ok;
      ok.x = f2bf(oacc[dg][4 * g + 0] * inv); ok.y = f2bf(oacc[dg][4 * g + 1] * inv);
      ok.z = f2bf(oacc[dg][4 * g + 2] * inv); ok.w = f2bf(oacc[dg][4 * g + 3] * inv);
      *(ushort4*)&sm.Ot[w * 32 + q5][dg * 32 + g * 8 + 4 * hi] = ok;
    }
  __syncthreads();
  {
    const int row = t >> 1, c32 = (t & 1) * 32;
    const size_t gb = ((size_t)(half * 32 + bh) * S_LEN + qt * 128 + row) * 64 + c32;
#pragma unroll
    for (int j = 0; j < 4; ++j)
      *(uint4*)&op[gb + j * 8] = *(const uint4*)&sm.Ot[row][c32 + j * 8];
  }
}

// ---------------- combine the two split-KV halves (weights = l_i) ----------------
__global__ void attn_combine(const ushort* __restrict__ op, const float* __restrict__ lso,
                             ushort* __restrict__ Ob) {
  const int idx = blockIdx.x * 256 + threadIdx.x;
  const int d8 = (idx & 7) * 8;
  const int row = idx >> 3;
  const int bh = row >> 11, q = row & 2047;
  const int b = bh >> 4, h = bh & 15;

  const float l1 = lso[row];
  const float l2 = lso[65536 + row];
  const float s = 1.0f / (l1 + l2);
  const float s1 = l1 * s, s2 = l2 * s;

  uint4 a = *(const uint4*)&op[(size_t)row * 64 + d8];
  uint4 c = *(const uint4*)&op[(size_t)(65536 + row) * 64 + d8];
  const uint32_t* aw = (const uint32_t*)&a;
  const uint32_t* cw = (const uint32_t*)&c;
  uint32_t o[4];
#pragma unroll
  for (int j = 0; j < 4; ++j) {
    float lo = s1 * bf2f_lo(aw[j]) + s2 * bf2f_lo(cw[j]);
    float hi = s1 * bf2f_hi(aw[j]) + s2 * bf2f_hi(cw[j]);
    o[j] = (uint32_t)f2bf(lo) | ((uint32_t)f2bf(hi) << 16);
  }
  *(uint4*)&Ob[((size_t)(b * S_LEN + q)) * DM + h * 64 + d8] = *(const uint4*)o;
}

extern "C" void kernel_launch(void* const* d_in, const int* in_sizes, int n_in,
                              void* d_out, int out_size, void* d_ws, size_t ws_size,
                              hipStream_t stream) {
  const float* x     = (const float*)d_in[0];
  const float* w_qkv = (const float*)d_in[2];
  const float* w_out = (const float*)d_in[3];
  float* out = (float*)d_out;

  char* ws = (char*)d_ws;
  ushort* xb    = (ushort*)(ws);
  ushort* wqkvb = (ushort*)(ws + 8388608);
  ushort* woutb = (ushort*)(ws + 14680064);
  ushort* Qh    = (ushort*)(ws + 41943040);
  ushort* Kh    = (ushort*)(ws + 50331648);
  ushort* Vt    = (ushort*)(ws + 58720256);
  ushort* Ob    = (ushort*)(ws + 67108864);
  float2* tab   = (float2*)(ws + 75497472);
  ushort* op    = (ushort*)(ws + 16777216);   // 16 MB: (2,32,2048,64) bf16
  float*  lso   = (float*)(ws + 33554432);    // 512 KB: (2,32,2048) float

  prep<<<2048, 256, 0, stream>>>(x, w_qkv, w_out, xb, wqkvb, woutb, tab);

  gemm_qkv<<<dim3(24, 32), 256, 0, stream>>>(xb, wqkvb, tab, Qh, Kh, Vt);

  flash_attn7<<<dim3(32, 16, 2), 256, 0, stream>>>(Qh, Kh, Vt, op, lso);
  attn_combine<<<2048, 256, 0, stream>>>(op, lso, Ob);

  gemm_bt4<0><<<dim3(8, 32), 256, 0, stream>>>(Ob, woutb, out, 4096, 1024, 1024);
}

// Round 15
// 106.105 us; speedup vs baseline: 1.2198x; 1.0535x over previous
//
#include <hip/hip_runtime.h>
#include <hip/hip_bf16.h>
#include <cstdint>

typedef __attribute__((ext_vector_type(8))) __bf16 bf16x8;
typedef __attribute__((ext_vector_type(4))) float f32x4;
typedef __attribute__((ext_vector_type(16))) float f32x16;

#define DM 1024
#define NH 16
#define DH 64
#define S_LEN 2048
#define BATCH 2

__device__ __forceinline__ ushort f2bf(float f) {
  union { float f; uint32_t u; } v; v.f = f;
  uint32_t u = v.u;
  uint32_t r = (u + 0x7fffu + ((u >> 16) & 1u)) >> 16;
  return (ushort)r;
}
__device__ __forceinline__ float bf2f(ushort h) {
  union { uint32_t u; float f; } v; v.u = ((uint32_t)h) << 16;
  return v.f;
}
__device__ __forceinline__ float bf2f_lo(uint32_t u) {
  union { uint32_t u; float f; } v; v.u = u << 16;
  return v.f;
}
__device__ __forceinline__ float bf2f_hi(uint32_t u) {
  union { uint32_t u; float f; } v; v.u = u & 0xffff0000u;
  return v.f;
}

__device__ __forceinline__ void gload16(const void* g, void* l) {
  __builtin_amdgcn_global_load_lds(
      (const __attribute__((address_space(1))) unsigned*)g,
      (__attribute__((address_space(3))) unsigned*)l, 16, 0, 0);
}

__device__ __forceinline__ float tsum16(const f32x16& v) {
  float a = (v[0] + v[1]) + (v[2] + v[3]);
  float b = (v[4] + v[5]) + (v[6] + v[7]);
  float c = (v[8] + v[9]) + (v[10] + v[11]);
  float d = (v[12] + v[13]) + (v[14] + v[15]);
  return (a + b) + (c + d);
}

// ---------------- prep: all f32->bf16 casts + rope table in one kernel ----------------
__global__ void prep(const float* __restrict__ x, const float* __restrict__ wqkv,
                     const float* __restrict__ wout,
                     ushort* __restrict__ xb, ushort* __restrict__ wqkvb,
                     ushort* __restrict__ woutb, float2* __restrict__ tab) {
  const int NX = 1048576, NW = 786432, NO = 262144, NT = 65536;
  for (int i = blockIdx.x * blockDim.x + threadIdx.x; i < NX + NW + NO + NT;
       i += gridDim.x * blockDim.x) {
    if (i < NX + NW + NO) {
      const float* src; ushort* dst; int j;
      if (i < NX)           { src = x;    dst = xb;    j = i; }
      else if (i < NX + NW) { src = wqkv; dst = wqkvb; j = i - NX; }
      else                  { src = wout; dst = woutb; j = i - NX - NW; }
      float4 v = ((const float4*)src)[j];
      ushort4 o;
      o.x = f2bf(v.x); o.y = f2bf(v.y); o.z = f2bf(v.z); o.w = f2bf(v.w);
      ((ushort4*)dst)[j] = o;
    } else {
      int j = i - NX - NW - NO;
      int fi = j & 31, s = j >> 5;
      float inv = expf(-(float)fi * (9.210340371976184f / 32.0f));
      float ang = (float)s * inv;
      float sn, cs;
      sincosf(ang, &sn, &cs);
      tab[j] = make_float2(cs, sn);
    }
  }
}

// ---------------- fused QKV GEMM + LDS-staged rope/transpose epilogue (unchanged) ----------------
__global__ __launch_bounds__(256) void gemm_qkv(
    const ushort* __restrict__ A, const ushort* __restrict__ B,
    const float2* __restrict__ tab,
    ushort* __restrict__ Qh, ushort* __restrict__ Kh, ushort* __restrict__ Vt)
{
  union SM {
    struct { ushort As[128][64]; ushort Bs[128][64]; } s;
    ushort vt[128][136];
  };
  __shared__ __align__(16) SM sm;

  const int K = 1024;
  const int t = threadIdx.x;
  const int w = t >> 6, lane = t & 63;
  const int wm = w >> 1, wn = w & 1;
  const int lr = lane & 15, lk = lane >> 4;
  const int m0 = blockIdx.y * 128, n0 = blockIdx.x * 128;

  const int srow8 = lane >> 3;
  const int scol  = ((lane & 7) ^ srow8) * 8;

  f32x4 acc[4][4];
#pragma unroll
  for (int m = 0; m < 4; m++)
#pragma unroll
    for (int n = 0; n < 4; n++) acc[m][n] = (f32x4)(0.0f);

  for (int k0 = 0; k0 < K; k0 += 64) {
#pragma unroll
    for (int j = 0; j < 4; ++j) {
      const int c = w * 4 + j;
      const int row = c * 8 + srow8;
      gload16(&A[(size_t)(m0 + row) * K + k0 + scol], &sm.s.As[c * 8][0]);
      gload16(&B[(size_t)(n0 + row) * K + k0 + scol], &sm.s.Bs[c * 8][0]);
    }
    __syncthreads();

    bf16x8 af[4][2], bfr[4][2];
#pragma unroll
    for (int m = 0; m < 4; m++)
#pragma unroll
      for (int kk = 0; kk < 2; kk++) {
        const int ch = (((kk << 2) + lk) ^ (lr & 7)) * 8;
        af[m][kk] = *(const bf16x8*)&sm.s.As[wm * 64 + m * 16 + lr][ch];
      }
#pragma unroll
    for (int n = 0; n < 4; n++)
#pragma unroll
      for (int kk = 0; kk < 2; kk++) {
        const int ch = (((kk << 2) + lk) ^ (lr & 7)) * 8;
        bfr[n][kk] = *(const bf16x8*)&sm.s.Bs[wn * 64 + n * 16 + lr][ch];
      }

    __builtin_amdgcn_s_setprio(1);
#pragma unroll
    for (int kk = 0; kk < 2; kk++)
#pragma unroll
      for (int m = 0; m < 4; m++)
#pragma unroll
        for (int n = 0; n < 4; n++)
          acc[m][n] = __builtin_amdgcn_mfma_f32_16x16x32_bf16(af[m][kk], bfr[n][kk], acc[m][n], 0, 0, 0);
    __builtin_amdgcn_s_setprio(0);

    __syncthreads();
  }

  const int reg  = n0 >> 10;
  const int cb   = n0 & 1023;
  const int b    = m0 >> 11;
  const int s0   = m0 & 2047;
  const int h0   = cb >> 6;

#pragma unroll
  for (int m = 0; m < 4; m++)
#pragma unroll
    for (int n = 0; n < 4; n++)
#pragma unroll
      for (int r = 0; r < 4; r++)
        sm.vt[wm * 64 + m * 16 + lk * 4 + r][wn * 64 + n * 16 + lr] = f2bf(acc[m][n][r]);
  __syncthreads();

  if (reg < 2) {
    ushort* dst = reg ? Kh : Qh;
    const float qs = reg ? 1.0f : 0.125f * 1.4426950408889634f;
#pragma unroll
    for (int p = 0; p < 8; ++p) {
      const int tid = t + p * 256;
      const int srow = tid >> 4;
      const int c8 = tid & 15;
      const int h = h0 + (c8 >> 3), d8 = (c8 & 7) * 8;
      const int s = s0 + srow;
      const ushort* lp = &sm.vt[srow][c8 * 8];
      float4 t0 = *(const float4*)&tab[s * 32 + (c8 & 7) * 4];
      float4 t1 = *(const float4*)&tab[s * 32 + (c8 & 7) * 4 + 2];
      uint32_t ow[4];
#pragma unroll
      for (int j = 0; j < 4; ++j) {
        float2 cs2 = (j < 2) ? ((const float2*)&t0)[j] : ((const float2*)&t1)[j - 2];
        float xr = bf2f(lp[2 * j]), xi = bf2f(lp[2 * j + 1]);
        float orr = (xr * cs2.x - xi * cs2.y) * qs;
        float oii = (xr * cs2.y + xi * cs2.x) * qs;
        ow[j] = (uint32_t)f2bf(orr) | ((uint32_t)f2bf(oii) << 16);
      }
      *(uint4*)&dst[((size_t)((b * NH + h) * S_LEN + s)) * 64 + d8] = *(const uint4*)ow;
    }
  } else {
#pragma unroll
    for (int p = 0; p < 8; ++p) {
      const int tid = t + p * 256;
      const int cl = tid >> 4;
      const int s8 = (tid & 15) * 8;
      const int h = h0 + (cl >> 6), d = cl & 63;
      ushort tmp[8];
#pragma unroll
      for (int j = 0; j < 8; j++) tmp[j] = sm.vt[s8 + j][cl];
      *(uint4*)&Vt[((size_t)((b * NH + h) * 64 + d)) * S_LEN + s0 + s8] = *(const uint4*)tmp;
    }
  }
}

// ---------------- GEMM v4 (async-staged, for out-proj, unchanged) ----------------
template<int WRITE_BF16>
__global__ __launch_bounds__(256) void gemm_bt4(
    const ushort* __restrict__ A, const ushort* __restrict__ B,
    void* __restrict__ Cv, int M, int N, int K)
{
  __shared__ ushort As[128][64];
  __shared__ ushort Bs[128][64];
  const int t = threadIdx.x;
  const int w = t >> 6, lane = t & 63;
  const int wm = w >> 1, wn = w & 1;
  const int lr = lane & 15, lk = lane >> 4;
  const int m0 = blockIdx.y * 128, n0 = blockIdx.x * 128;

  const int srow8 = lane >> 3;
  const int scol  = ((lane & 7) ^ srow8) * 8;

  f32x4 acc[4][4];
#pragma unroll
  for (int m = 0; m < 4; m++)
#pragma unroll
    for (int n = 0; n < 4; n++) acc[m][n] = (f32x4)(0.0f);

  for (int k0 = 0; k0 < K; k0 += 64) {
#pragma unroll
    for (int j = 0; j < 4; ++j) {
      const int c = w * 4 + j;
      const int row = c * 8 + srow8;
      gload16(&A[(size_t)(m0 + row) * K + k0 + scol], &As[c * 8][0]);
      gload16(&B[(size_t)(n0 + row) * K + k0 + scol], &Bs[c * 8][0]);
    }
    __syncthreads();

    bf16x8 af[4][2], bfr[4][2];
#pragma unroll
    for (int m = 0; m < 4; m++)
#pragma unroll
      for (int kk = 0; kk < 2; kk++) {
        const int ch = (((kk << 2) + lk) ^ (lr & 7)) * 8;
        af[m][kk] = *(const bf16x8*)&As[wm * 64 + m * 16 + lr][ch];
      }
#pragma unroll
    for (int n = 0; n < 4; n++)
#pragma unroll
      for (int kk = 0; kk < 2; kk++) {
        const int ch = (((kk << 2) + lk) ^ (lr & 7)) * 8;
        bfr[n][kk] = *(const bf16x8*)&Bs[wn * 64 + n * 16 + lr][ch];
      }

    __builtin_amdgcn_s_setprio(1);
#pragma unroll
    for (int kk = 0; kk < 2; kk++)
#pragma unroll
      for (int m = 0; m < 4; m++)
#pragma unroll
        for (int n = 0; n < 4; n++)
          acc[m][n] = __builtin_amdgcn_mfma_f32_16x16x32_bf16(af[m][kk], bfr[n][kk], acc[m][n], 0, 0, 0);
    __builtin_amdgcn_s_setprio(0);

    __syncthreads();
  }

#pragma unroll
  for (int m = 0; m < 4; m++) {
    int row = m0 + wm * 64 + m * 16 + lk * 4;
#pragma unroll
    for (int n = 0; n < 4; n++) {
      int col = n0 + wn * 64 + n * 16 + lr;
#pragma unroll
      for (int r = 0; r < 4; r++) {
        float val = acc[m][n][r];
        if (WRITE_BF16) ((ushort*)Cv)[(size_t)(row + r) * N + col] = f2bf(val);
        else            ((float*)Cv)[(size_t)(row + r) * N + col] = val;
      }
    }
  }
}

// ---------------- causal flash attention v8: in-block split-KV merge ----------------
// 512 threads, 8 waves. Waves 0-3 (half 0): k-tiles [0,qt+1); waves 4-7 (half 1):
// [qt+1,2qt+2). Both halves run exactly qt+1 iterations -> shared barriers align.
// Each half has its own 32 KB K/V double-buffer. Epilogue: raw (unnormalized) O
// in bf16 + per-row l to LDS; merged (O1+O2)/(l1+l2) written straight to Ob.
// Fixed-m softmax (scores bounded), T12 cvt_pk+permlane, balanced qt pairing.
union SMemU8 {
  struct { ushort K[2][2][64][64]; ushort V[2][2][64][64]; } kv;  // [half][buf] 64 KB
  struct { ushort O[2][128][68]; float l[2][128]; } ep;           // ~35.8 KB
};

__global__ __launch_bounds__(512) void flash_attn8(
    const ushort* __restrict__ Qh, const ushort* __restrict__ Kh, const ushort* __restrict__ Vt,
    ushort* __restrict__ Ob)
{
  __shared__ __align__(16) SMemU8 sm;

  const int bh = blockIdx.x;                     // XCD = bh % 8
  const int y = blockIdx.y;
  const int qt = (y < 8) ? (15 - y) : (y - 8);   // balanced pairing: pairs sum to 17 iters
  const int b = bh >> 4, h = bh & 15;
  const int t = threadIdx.x;
  const int w = t >> 6, lane = t & 63;
  const int half = w >> 2, ws = w & 3;
  const int q5 = lane & 31, hi = lane >> 5;

  const int qbase_w = qt * 128 + ws * 32;
  const int qg = qbase_w + q5;

  bf16x8 qreg[4];
  {
    const size_t qb = ((size_t)bh * S_LEN + qg) * 64;
#pragma unroll
    for (int c = 0; c < 4; ++c)
      qreg[c] = *(const bf16x8*)&Qh[qb + c * 16 + hi * 8];
  }

  f32x16 oacc[2];
  oacc[0] = (f32x16)(0.0f); oacc[1] = (f32x16)(0.0f);
  float lsum = 0.0f;

  const ushort* Kg = &Kh[((size_t)bh * S_LEN) * 64];
  const ushort* Vg = &Vt[((size_t)bh * 64) * S_LEN];

  // per-half STAGE: each half's 4 waves stage its own 64x64 K and V tiles
  auto STAGE = [&](int bf, int jt) {
#pragma unroll
    for (int p = 0; p < 2; ++p) {
      const int row = ws * 16 + p * 8 + (lane >> 3);
      const int c16 = (lane & 7) ^ (row & 7);
      gload16(&Kg[((size_t)(jt * 64 + row)) * 64 + c16 * 8], &sm.kv.K[half][bf][ws * 16 + p * 8][0]);
      gload16(&Vg[((size_t)row) * S_LEN + jt * 64 + c16 * 8], &sm.kv.V[half][bf][ws * 16 + p * 8][0]);
    }
  };

  const int j0 = half ? (qt + 1) : 0;

  STAGE(0, j0);
  __syncthreads();

  int cur = 0;
  for (int i = 0; i <= qt; ++i) {
    if (i < qt) STAGE(cur ^ 1, j0 + i + 1);

    const int jt = j0 + i;
    const bool active = (jt * 64 <= qbase_w + 31);   // wave-uniform
    if (active) {
      f32x16 sc[2];
      sc[0] = (f32x16)(0.0f); sc[1] = (f32x16)(0.0f);
      __builtin_amdgcn_s_setprio(1);
#pragma unroll
      for (int kg = 0; kg < 2; ++kg) {
        const int kr = kg * 32 + q5;
#pragma unroll
        for (int c = 0; c < 4; ++c) {
          bf16x8 kf = *(const bf16x8*)&sm.kv.K[half][cur][kr][((c * 2 + hi) ^ (kr & 7)) * 8];
          sc[kg] = __builtin_amdgcn_mfma_f32_32x32x16_bf16(kf, qreg[c], sc[kg], 0, 0, 0);
        }
      }
      __builtin_amdgcn_s_setprio(0);

      if (jt * 64 + 63 > qbase_w) {
        const int kb = jt * 64;
#pragma unroll
        for (int r = 0; r < 16; ++r) {
          const int kl = kb + (r & 3) + 8 * (r >> 2) + 4 * hi;
          if (kl > qg)      sc[0][r] = -1e30f;
          if (kl + 32 > qg) sc[1][r] = -1e30f;
        }
      }

#pragma unroll
      for (int kg = 0; kg < 2; ++kg)
#pragma unroll
        for (int r = 0; r < 16; ++r)
          sc[kg][r] = __builtin_amdgcn_exp2f(sc[kg][r]);
      float rsum = tsum16(sc[0]) + tsum16(sc[1]);
      rsum += __shfl_xor(rsum, 32, 64);
      lsum += rsum;

      bf16x8 pf[4];
#pragma unroll
      for (int kc = 0; kc < 4; ++kc) {
        const int kg = kc >> 1, rA = (kc & 1) * 8, rB = rA + 4;
        uint32_t A0, A1, B0, B1;
        asm("v_cvt_pk_bf16_f32 %0, %1, %2" : "=v"(A0) : "v"(sc[kg][rA + 0]), "v"(sc[kg][rA + 1]));
        asm("v_cvt_pk_bf16_f32 %0, %1, %2" : "=v"(A1) : "v"(sc[kg][rA + 2]), "v"(sc[kg][rA + 3]));
        asm("v_cvt_pk_bf16_f32 %0, %1, %2" : "=v"(B0) : "v"(sc[kg][rB + 0]), "v"(sc[kg][rB + 1]));
        asm("v_cvt_pk_bf16_f32 %0, %1, %2" : "=v"(B1) : "v"(sc[kg][rB + 2]), "v"(sc[kg][rB + 3]));
        asm("v_permlane32_swap_b32 %0, %1" : "+v"(A0), "+v"(B0));
        asm("v_permlane32_swap_b32 %0, %1" : "+v"(A1), "+v"(B1));
        union { uint32_t u[4]; bf16x8 v; } cv;
        cv.u[0] = A0; cv.u[1] = A1; cv.u[2] = B0; cv.u[3] = B1;
        pf[kc] = cv.v;
      }

      __builtin_amdgcn_s_setprio(1);
#pragma unroll
      for (int dg = 0; dg < 2; ++dg) {
        const int vr = dg * 32 + q5;
#pragma unroll
        for (int kc = 0; kc < 4; ++kc) {
          bf16x8 vf = *(const bf16x8*)&sm.kv.V[half][cur][vr][((kc * 2 + hi) ^ (vr & 7)) * 8];
          oacc[dg] = __builtin_amdgcn_mfma_f32_32x32x16_bf16(vf, pf[kc], oacc[dg], 0, 0, 0);
        }
      }
      __builtin_amdgcn_s_setprio(0);
    }

    __syncthreads();
    cur ^= 1;
  }

  // ---- epilogue: raw O + l to LDS (after final barrier, kv is dead) ----
  if (hi == 0)
    sm.ep.l[half][ws * 32 + q5] = lsum;
#pragma unroll
  for (int dg = 0; dg < 2; ++dg)
#pragma unroll
    for (int g = 0; g < 4; ++g) {
      ushort4 ok;
      ok.x = f2bf(oacc[dg][4 * g + 0]); ok.y = f2bf(oacc[dg][4 * g + 1]);
      ok.z = f2bf(oacc[dg][4 * g + 2]); ok.w = f2bf(oacc[dg][4 * g + 3]);
      *(ushort4*)&sm.ep.O[half][ws * 32 + q5][dg * 32 + g * 8 + 4 * hi] = ok;
    }
  __syncthreads();

  // ---- merge halves + store: 512 threads x 16 d-elements ----
  {
    const int row = t >> 2;             // 0..127
    const int dc = (t & 3) * 16;        // 0,16,32,48
    const float s = 1.0f / (sm.ep.l[0][row] + sm.ep.l[1][row]);
    const uint32_t* a = (const uint32_t*)&sm.ep.O[0][row][dc];
    const uint32_t* c = (const uint32_t*)&sm.ep.O[1][row][dc];
    uint32_t o[8];
#pragma unroll
    for (int j = 0; j < 8; ++j) {
      float lo = (bf2f_lo(a[j]) + bf2f_lo(c[j])) * s;
      float hv = (bf2f_hi(a[j]) + bf2f_hi(c[j])) * s;
      o[j] = (uint32_t)f2bf(lo) | ((uint32_t)f2bf(hv) << 16);
    }
    const size_t gb = ((size_t)(b * S_LEN + qt * 128 + row)) * DM + h * 64 + dc;
    *(uint4*)&Ob[gb]     = *(const uint4*)&o[0];
    *(uint4*)&Ob[gb + 8] = *(const uint4*)&o[4];
  }
}

extern "C" void kernel_launch(void* const* d_in, const int* in_sizes, int n_in,
                              void* d_out, int out_size, void* d_ws, size_t ws_size,
                              hipStream_t stream) {
  const float* x     = (const float*)d_in[0];
  const float* w_qkv = (const float*)d_in[2];
  const float* w_out = (const float*)d_in[3];
  float* out = (float*)d_out;

  char* ws = (char*)d_ws;
  ushort* xb    = (ushort*)(ws);
  ushort* wqkvb = (ushort*)(ws + 8388608);
  ushort* woutb = (ushort*)(ws + 14680064);
  ushort* Qh    = (ushort*)(ws + 41943040);
  ushort* Kh    = (ushort*)(ws + 50331648);
  ushort* Vt    = (ushort*)(ws + 58720256);
  ushort* Ob    = (ushort*)(ws + 67108864);
  float2* tab   = (float2*)(ws + 75497472);

  prep<<<2048, 256, 0, stream>>>(x, w_qkv, w_out, xb, wqkvb, woutb, tab);

  gemm_qkv<<<dim3(24, 32), 256, 0, stream>>>(xb, wqkvb, tab, Qh, Kh, Vt);

  // grid: x = bh (32), y = 16 (balanced qt pairing)
  flash_attn8<<<dim3(32, 16), 512, 0, stream>>>(Qh, Kh, Vt, Ob);

  gemm_bt4<0><<<dim3(8, 32), 256, 0, stream>>>(Ob, woutb, out, 4096, 1024, 1024);
}

// Round 16
// 101.060 us; speedup vs baseline: 1.2807x; 1.0499x over previous
//
#include <hip/hip_runtime.h>
#include <hip/hip_bf16.h>
#include <cstdint>

typedef __attribute__((ext_vector_type(8))) __bf16 bf16x8;
typedef __attribute__((ext_vector_type(4))) float f32x4;
typedef __attribute__((ext_vector_type(16))) float f32x16;

#define DM 1024
#define NH 16
#define DH 64
#define S_LEN 2048
#define BATCH 2

__device__ __forceinline__ ushort f2bf(float f) {
  union { float f; uint32_t u; } v; v.f = f;
  uint32_t u = v.u;
  uint32_t r = (u + 0x7fffu + ((u >> 16) & 1u)) >> 16;
  return (ushort)r;
}
__device__ __forceinline__ float bf2f(ushort h) {
  union { uint32_t u; float f; } v; v.u = ((uint32_t)h) << 16;
  return v.f;
}
__device__ __forceinline__ float bf2f_lo(uint32_t u) {
  union { uint32_t u; float f; } v; v.u = u << 16;
  return v.f;
}
__device__ __forceinline__ float bf2f_hi(uint32_t u) {
  union { uint32_t u; float f; } v; v.u = u & 0xffff0000u;
  return v.f;
}

__device__ __forceinline__ void gload16(const void* g, void* l) {
  __builtin_amdgcn_global_load_lds(
      (const __attribute__((address_space(1))) unsigned*)g,
      (__attribute__((address_space(3))) unsigned*)l, 16, 0, 0);
}

__device__ __forceinline__ float tsum16(const f32x16& v) {
  float a = (v[0] + v[1]) + (v[2] + v[3]);
  float b = (v[4] + v[5]) + (v[6] + v[7]);
  float c = (v[8] + v[9]) + (v[10] + v[11]);
  float d = (v[12] + v[13]) + (v[14] + v[15]);
  return (a + b) + (c + d);
}

// ---------------- prep: all f32->bf16 casts + rope table in one kernel ----------------
__global__ void prep(const float* __restrict__ x, const float* __restrict__ wqkv,
                     const float* __restrict__ wout,
                     ushort* __restrict__ xb, ushort* __restrict__ wqkvb,
                     ushort* __restrict__ woutb, float2* __restrict__ tab) {
  const int NX = 1048576, NW = 786432, NO = 262144, NT = 65536;
  for (int i = blockIdx.x * blockDim.x + threadIdx.x; i < NX + NW + NO + NT;
       i += gridDim.x * blockDim.x) {
    if (i < NX + NW + NO) {
      const float* src; ushort* dst; int j;
      if (i < NX)           { src = x;    dst = xb;    j = i; }
      else if (i < NX + NW) { src = wqkv; dst = wqkvb; j = i - NX; }
      else                  { src = wout; dst = woutb; j = i - NX - NW; }
      float4 v = ((const float4*)src)[j];
      ushort4 o;
      o.x = f2bf(v.x); o.y = f2bf(v.y); o.z = f2bf(v.z); o.w = f2bf(v.w);
      ((ushort4*)dst)[j] = o;
    } else {
      int j = i - NX - NW - NO;
      int fi = j & 31, s = j >> 5;
      float inv = expf(-(float)fi * (9.210340371976184f / 32.0f));
      float ang = (float)s * inv;
      float sn, cs;
      sincosf(ang, &sn, &cs);
      tab[j] = make_float2(cs, sn);
    }
  }
}

// ---------------- fused QKV GEMM + LDS-staged rope/transpose epilogue (unchanged) ----------------
__global__ __launch_bounds__(256) void gemm_qkv(
    const ushort* __restrict__ A, const ushort* __restrict__ B,
    const float2* __restrict__ tab,
    ushort* __restrict__ Qh, ushort* __restrict__ Kh, ushort* __restrict__ Vt)
{
  union SM {
    struct { ushort As[128][64]; ushort Bs[128][64]; } s;
    ushort vt[128][136];
  };
  __shared__ __align__(16) SM sm;

  const int K = 1024;
  const int t = threadIdx.x;
  const int w = t >> 6, lane = t & 63;
  const int wm = w >> 1, wn = w & 1;
  const int lr = lane & 15, lk = lane >> 4;
  const int m0 = blockIdx.y * 128, n0 = blockIdx.x * 128;

  const int srow8 = lane >> 3;
  const int scol  = ((lane & 7) ^ srow8) * 8;

  f32x4 acc[4][4];
#pragma unroll
  for (int m = 0; m < 4; m++)
#pragma unroll
    for (int n = 0; n < 4; n++) acc[m][n] = (f32x4)(0.0f);

  for (int k0 = 0; k0 < K; k0 += 64) {
#pragma unroll
    for (int j = 0; j < 4; ++j) {
      const int c = w * 4 + j;
      const int row = c * 8 + srow8;
      gload16(&A[(size_t)(m0 + row) * K + k0 + scol], &sm.s.As[c * 8][0]);
      gload16(&B[(size_t)(n0 + row) * K + k0 + scol], &sm.s.Bs[c * 8][0]);
    }
    __syncthreads();

    bf16x8 af[4][2], bfr[4][2];
#pragma unroll
    for (int m = 0; m < 4; m++)
#pragma unroll
      for (int kk = 0; kk < 2; kk++) {
        const int ch = (((kk << 2) + lk) ^ (lr & 7)) * 8;
        af[m][kk] = *(const bf16x8*)&sm.s.As[wm * 64 + m * 16 + lr][ch];
      }
#pragma unroll
    for (int n = 0; n < 4; n++)
#pragma unroll
      for (int kk = 0; kk < 2; kk++) {
        const int ch = (((kk << 2) + lk) ^ (lr & 7)) * 8;
        bfr[n][kk] = *(const bf16x8*)&sm.s.Bs[wn * 64 + n * 16 + lr][ch];
      }

    __builtin_amdgcn_s_setprio(1);
#pragma unroll
    for (int kk = 0; kk < 2; kk++)
#pragma unroll
      for (int m = 0; m < 4; m++)
#pragma unroll
        for (int n = 0; n < 4; n++)
          acc[m][n] = __builtin_amdgcn_mfma_f32_16x16x32_bf16(af[m][kk], bfr[n][kk], acc[m][n], 0, 0, 0);
    __builtin_amdgcn_s_setprio(0);

    __syncthreads();
  }

  const int reg  = n0 >> 10;
  const int cb   = n0 & 1023;
  const int b    = m0 >> 11;
  const int s0   = m0 & 2047;
  const int h0   = cb >> 6;

#pragma unroll
  for (int m = 0; m < 4; m++)
#pragma unroll
    for (int n = 0; n < 4; n++)
#pragma unroll
      for (int r = 0; r < 4; r++)
        sm.vt[wm * 64 + m * 16 + lk * 4 + r][wn * 64 + n * 16 + lr] = f2bf(acc[m][n][r]);
  __syncthreads();

  if (reg < 2) {
    ushort* dst = reg ? Kh : Qh;
    const float qs = reg ? 1.0f : 0.125f * 1.4426950408889634f;
#pragma unroll
    for (int p = 0; p < 8; ++p) {
      const int tid = t + p * 256;
      const int srow = tid >> 4;
      const int c8 = tid & 15;
      const int h = h0 + (c8 >> 3), d8 = (c8 & 7) * 8;
      const int s = s0 + srow;
      const ushort* lp = &sm.vt[srow][c8 * 8];
      float4 t0 = *(const float4*)&tab[s * 32 + (c8 & 7) * 4];
      float4 t1 = *(const float4*)&tab[s * 32 + (c8 & 7) * 4 + 2];
      uint32_t ow[4];
#pragma unroll
      for (int j = 0; j < 4; ++j) {
        float2 cs2 = (j < 2) ? ((const float2*)&t0)[j] : ((const float2*)&t1)[j - 2];
        float xr = bf2f(lp[2 * j]), xi = bf2f(lp[2 * j + 1]);
        float orr = (xr * cs2.x - xi * cs2.y) * qs;
        float oii = (xr * cs2.y + xi * cs2.x) * qs;
        ow[j] = (uint32_t)f2bf(orr) | ((uint32_t)f2bf(oii) << 16);
      }
      *(uint4*)&dst[((size_t)((b * NH + h) * S_LEN + s)) * 64 + d8] = *(const uint4*)ow;
    }
  } else {
#pragma unroll
    for (int p = 0; p < 8; ++p) {
      const int tid = t + p * 256;
      const int cl = tid >> 4;
      const int s8 = (tid & 15) * 8;
      const int h = h0 + (cl >> 6), d = cl & 63;
      ushort tmp[8];
#pragma unroll
      for (int j = 0; j < 8; j++) tmp[j] = sm.vt[s8 + j][cl];
      *(uint4*)&Vt[((size_t)((b * NH + h) * 64 + d)) * S_LEN + s0 + s8] = *(const uint4*)tmp;
    }
  }
}

// ---------------- out-proj GEMM v2: in-block K-split (waves 0-3: k<512, 4-7: k>=512) ----------------
// Grid (8,32) = 256 blocks = 1/CU, but 512 threads -> 2 waves/SIMD (was 1).
// Each K-group has its own 32 KB staging; groups share barriers (same loop count).
// Merge: group 1 writes f32 acc to LDS alias, barrier, group 0 adds + stores.
__global__ __launch_bounds__(512) void gemm_out2(
    const ushort* __restrict__ A, const ushort* __restrict__ B, float* __restrict__ Cv)
{
  union SM {
    struct { ushort As[2][128][64]; ushort Bs[2][128][64]; } s;  // [kgroup] 64 KB
    float accs[128][128];                                        // merge alias 64 KB
  };
  __shared__ __align__(16) SM sm;

  const int N = 1024, K = 1024;
  const int t = threadIdx.x;
  const int w = t >> 6, lane = t & 63;
  const int kg = w >> 2;            // K-group: 0 -> k<512, 1 -> k>=512
  const int wq = w & 3;             // quadrant wave within group
  const int wm = wq >> 1, wn = wq & 1;
  const int lr = lane & 15, lk = lane >> 4;
  const int m0 = blockIdx.y * 128, n0 = blockIdx.x * 128;

  const int srow8 = lane >> 3;
  const int scol  = ((lane & 7) ^ srow8) * 8;

  f32x4 acc[4][4];
#pragma unroll
  for (int m = 0; m < 4; m++)
#pragma unroll
    for (int n = 0; n < 4; n++) acc[m][n] = (f32x4)(0.0f);

  for (int s = 0; s < 8; ++s) {
    const int k0 = kg * 512 + s * 64;
#pragma unroll
    for (int j = 0; j < 4; ++j) {
      const int c = wq * 4 + j;
      const int row = c * 8 + srow8;
      gload16(&A[(size_t)(m0 + row) * K + k0 + scol], &sm.s.As[kg][c * 8][0]);
      gload16(&B[(size_t)(n0 + row) * K + k0 + scol], &sm.s.Bs[kg][c * 8][0]);
    }
    __syncthreads();

    bf16x8 af[4][2], bfr[4][2];
#pragma unroll
    for (int m = 0; m < 4; m++)
#pragma unroll
      for (int kk = 0; kk < 2; kk++) {
        const int ch = (((kk << 2) + lk) ^ (lr & 7)) * 8;
        af[m][kk] = *(const bf16x8*)&sm.s.As[kg][wm * 64 + m * 16 + lr][ch];
      }
#pragma unroll
    for (int n = 0; n < 4; n++)
#pragma unroll
      for (int kk = 0; kk < 2; kk++) {
        const int ch = (((kk << 2) + lk) ^ (lr & 7)) * 8;
        bfr[n][kk] = *(const bf16x8*)&sm.s.Bs[kg][wn * 64 + n * 16 + lr][ch];
      }

    __builtin_amdgcn_s_setprio(1);
#pragma unroll
    for (int kk = 0; kk < 2; kk++)
#pragma unroll
      for (int m = 0; m < 4; m++)
#pragma unroll
        for (int n = 0; n < 4; n++)
          acc[m][n] = __builtin_amdgcn_mfma_f32_16x16x32_bf16(af[m][kk], bfr[n][kk], acc[m][n], 0, 0, 0);
    __builtin_amdgcn_s_setprio(0);

    __syncthreads();
  }

  // ---- merge: group 1 -> LDS (staging dead after last barrier) ----
  if (kg == 1) {
#pragma unroll
    for (int m = 0; m < 4; m++)
#pragma unroll
      for (int n = 0; n < 4; n++)
#pragma unroll
        for (int r = 0; r < 4; r++)
          sm.accs[wm * 64 + m * 16 + lk * 4 + r][wn * 64 + n * 16 + lr] = acc[m][n][r];
  }
  __syncthreads();
  if (kg == 0) {
#pragma unroll
    for (int m = 0; m < 4; m++) {
      const int row = m0 + wm * 64 + m * 16 + lk * 4;
#pragma unroll
      for (int n = 0; n < 4; n++) {
        const int col = n0 + wn * 64 + n * 16 + lr;
#pragma unroll
        for (int r = 0; r < 4; r++) {
          float v = acc[m][n][r] + sm.accs[wm * 64 + m * 16 + lk * 4 + r][wn * 64 + n * 16 + lr];
          Cv[(size_t)(row + r) * N + col] = v;
        }
      }
    }
  }
}

// ---------------- causal flash attention v8: in-block split-KV merge (unchanged) ----------------
union SMemU8 {
  struct { ushort K[2][2][64][64]; ushort V[2][2][64][64]; } kv;  // [half][buf] 64 KB
  struct { ushort O[2][128][68]; float l[2][128]; } ep;
};

__global__ __launch_bounds__(512) void flash_attn8(
    const ushort* __restrict__ Qh, const ushort* __restrict__ Kh, const ushort* __restrict__ Vt,
    ushort* __restrict__ Ob)
{
  __shared__ __align__(16) SMemU8 sm;

  const int bh = blockIdx.x;
  const int y = blockIdx.y;
  const int qt = (y < 8) ? (15 - y) : (y - 8);
  const int b = bh >> 4, h = bh & 15;
  const int t = threadIdx.x;
  const int w = t >> 6, lane = t & 63;
  const int half = w >> 2, ws = w & 3;
  const int q5 = lane & 31, hi = lane >> 5;

  const int qbase_w = qt * 128 + ws * 32;
  const int qg = qbase_w + q5;

  bf16x8 qreg[4];
  {
    const size_t qb = ((size_t)bh * S_LEN + qg) * 64;
#pragma unroll
    for (int c = 0; c < 4; ++c)
      qreg[c] = *(const bf16x8*)&Qh[qb + c * 16 + hi * 8];
  }

  f32x16 oacc[2];
  oacc[0] = (f32x16)(0.0f); oacc[1] = (f32x16)(0.0f);
  float lsum = 0.0f;

  const ushort* Kg = &Kh[((size_t)bh * S_LEN) * 64];
  const ushort* Vg = &Vt[((size_t)bh * 64) * S_LEN];

  auto STAGE = [&](int bf, int jt) {
#pragma unroll
    for (int p = 0; p < 2; ++p) {
      const int row = ws * 16 + p * 8 + (lane >> 3);
      const int c16 = (lane & 7) ^ (row & 7);
      gload16(&Kg[((size_t)(jt * 64 + row)) * 64 + c16 * 8], &sm.kv.K[half][bf][ws * 16 + p * 8][0]);
      gload16(&Vg[((size_t)row) * S_LEN + jt * 64 + c16 * 8], &sm.kv.V[half][bf][ws * 16 + p * 8][0]);
    }
  };

  const int j0 = half ? (qt + 1) : 0;

  STAGE(0, j0);
  __syncthreads();

  int cur = 0;
  for (int i = 0; i <= qt; ++i) {
    if (i < qt) STAGE(cur ^ 1, j0 + i + 1);

    const int jt = j0 + i;
    const bool active = (jt * 64 <= qbase_w + 31);
    if (active) {
      f32x16 sc[2];
      sc[0] = (f32x16)(0.0f); sc[1] = (f32x16)(0.0f);
      __builtin_amdgcn_s_setprio(1);
#pragma unroll
      for (int kg = 0; kg < 2; ++kg) {
        const int kr = kg * 32 + q5;
#pragma unroll
        for (int c = 0; c < 4; ++c) {
          bf16x8 kf = *(const bf16x8*)&sm.kv.K[half][cur][kr][((c * 2 + hi) ^ (kr & 7)) * 8];
          sc[kg] = __builtin_amdgcn_mfma_f32_32x32x16_bf16(kf, qreg[c], sc[kg], 0, 0, 0);
        }
      }
      __builtin_amdgcn_s_setprio(0);

      if (jt * 64 + 63 > qbase_w) {
        const int kb = jt * 64;
#pragma unroll
        for (int r = 0; r < 16; ++r) {
          const int kl = kb + (r & 3) + 8 * (r >> 2) + 4 * hi;
          if (kl > qg)      sc[0][r] = -1e30f;
          if (kl + 32 > qg) sc[1][r] = -1e30f;
        }
      }

#pragma unroll
      for (int kg = 0; kg < 2; ++kg)
#pragma unroll
        for (int r = 0; r < 16; ++r)
          sc[kg][r] = __builtin_amdgcn_exp2f(sc[kg][r]);
      float rsum = tsum16(sc[0]) + tsum16(sc[1]);
      rsum += __shfl_xor(rsum, 32, 64);
      lsum += rsum;

      bf16x8 pf[4];
#pragma unroll
      for (int kc = 0; kc < 4; ++kc) {
        const int kg = kc >> 1, rA = (kc & 1) * 8, rB = rA + 4;
        uint32_t A0, A1, B0, B1;
        asm("v_cvt_pk_bf16_f32 %0, %1, %2" : "=v"(A0) : "v"(sc[kg][rA + 0]), "v"(sc[kg][rA + 1]));
        asm("v_cvt_pk_bf16_f32 %0, %1, %2" : "=v"(A1) : "v"(sc[kg][rA + 2]), "v"(sc[kg][rA + 3]));
        asm("v_cvt_pk_bf16_f32 %0, %1, %2" : "=v"(B0) : "v"(sc[kg][rB + 0]), "v"(sc[kg][rB + 1]));
        asm("v_cvt_pk_bf16_f32 %0, %1, %2" : "=v"(B1) : "v"(sc[kg][rB + 2]), "v"(sc[kg][rB + 3]));
        asm("v_permlane32_swap_b32 %0, %1" : "+v"(A0), "+v"(B0));
        asm("v_permlane32_swap_b32 %0, %1" : "+v"(A1), "+v"(B1));
        union { uint32_t u[4]; bf16x8 v; } cv;
        cv.u[0] = A0; cv.u[1] = A1; cv.u[2] = B0; cv.u[3] = B1;
        pf[kc] = cv.v;
      }

      __builtin_amdgcn_s_setprio(1);
#pragma unroll
      for (int dg = 0; dg < 2; ++dg) {
        const int vr = dg * 32 + q5;
#pragma unroll
        for (int kc = 0; kc < 4; ++kc) {
          bf16x8 vf = *(const bf16x8*)&sm.kv.V[half][cur][vr][((kc * 2 + hi) ^ (vr & 7)) * 8];
          oacc[dg] = __builtin_amdgcn_mfma_f32_32x32x16_bf16(vf, pf[kc], oacc[dg], 0, 0, 0);
        }
      }
      __builtin_amdgcn_s_setprio(0);
    }

    __syncthreads();
    cur ^= 1;
  }

  if (hi == 0)
    sm.ep.l[half][ws * 32 + q5] = lsum;
#pragma unroll
  for (int dg = 0; dg < 2; ++dg)
#pragma unroll
    for (int g = 0; g < 4; ++g) {
      ushort4 ok;
      ok.x = f2bf(oacc[dg][4 * g + 0]); ok.y = f2bf(oacc[dg][4 * g + 1]);
      ok.z = f2bf(oacc[dg][4 * g + 2]); ok.w = f2bf(oacc[dg][4 * g + 3]);
      *(ushort4*)&sm.ep.O[half][ws * 32 + q5][dg * 32 + g * 8 + 4 * hi] = ok;
    }
  __syncthreads();

  {
    const int row = t >> 2;
    const int dc = (t & 3) * 16;
    const float s = 1.0f / (sm.ep.l[0][row] + sm.ep.l[1][row]);
    const uint32_t* a = (const uint32_t*)&sm.ep.O[0][row][dc];
    const uint32_t* c = (const uint32_t*)&sm.ep.O[1][row][dc];
    uint32_t o[8];
#pragma unroll
    for (int j = 0; j < 8; ++j) {
      float lo = (bf2f_lo(a[j]) + bf2f_lo(c[j])) * s;
      float hv = (bf2f_hi(a[j]) + bf2f_hi(c[j])) * s;
      o[j] = (uint32_t)f2bf(lo) | ((uint32_t)f2bf(hv) << 16);
    }
    const size_t gb = ((size_t)(b * S_LEN + qt * 128 + row)) * DM + h * 64 + dc;
    *(uint4*)&Ob[gb]     = *(const uint4*)&o[0];
    *(uint4*)&Ob[gb + 8] = *(const uint4*)&o[4];
  }
}

extern "C" void kernel_launch(void* const* d_in, const int* in_sizes, int n_in,
                              void* d_out, int out_size, void* d_ws, size_t ws_size,
                              hipStream_t stream) {
  const float* x     = (const float*)d_in[0];
  const float* w_qkv = (const float*)d_in[2];
  const float* w_out = (const float*)d_in[3];
  float* out = (float*)d_out;

  char* ws = (char*)d_ws;
  ushort* xb    = (ushort*)(ws);
  ushort* wqkvb = (ushort*)(ws + 8388608);
  ushort* woutb = (ushort*)(ws + 14680064);
  ushort* Qh    = (ushort*)(ws + 41943040);
  ushort* Kh    = (ushort*)(ws + 50331648);
  ushort* Vt    = (ushort*)(ws + 58720256);
  ushort* Ob    = (ushort*)(ws + 67108864);
  float2* tab   = (float2*)(ws + 75497472);

  prep<<<2048, 256, 0, stream>>>(x, w_qkv, w_out, xb, wqkvb, woutb, tab);

  gemm_qkv<<<dim3(24, 32), 256, 0, stream>>>(xb, wqkvb, tab, Qh, Kh, Vt);

  flash_attn8<<<dim3(32, 16), 512, 0, stream>>>(Qh, Kh, Vt, Ob);

  gemm_out2<<<dim3(8, 32), 512, 0, stream>>>(Ob, woutb, out);
}